// Round 3
// baseline (370139.111 us; speedup 1.0000x reference)
//
#include <hip/hip_runtime.h>
#include <stdint.h>

#define HID 1024
#define NLAYERS 8
#define NLET 100
#define T_TOTAL 4096

typedef uint32_t u32x4 __attribute__((ext_vector_type(4)));

// ---------- helpers ----------
__device__ __forceinline__ uint32_t f2bf(float f) {
    uint32_t u = __float_as_uint(f);
    return (u + 0x7FFFu + ((u >> 16) & 1u)) >> 16;
}
__device__ __forceinline__ float bflo(uint32_t p) { return __uint_as_float(p << 16); }
__device__ __forceinline__ float bfhi(uint32_t p) { return __uint_as_float(p & 0xFFFF0000u); }
__device__ __forceinline__ float sigm(float x) { return 1.0f / (1.0f + __expf(-x)); }
__device__ __forceinline__ float tanh_f(float x) {
    float xx = fminf(fmaxf(x, -15.0f), 15.0f);
    float e = __expf(2.0f * xx);
    return (e - 1.0f) / (e + 1.0f);
}
// signed byte b (0..3) of word w, as float
#define SBYTE(w, b) ((float)((int)((w) << (24 - 8 * (b))) >> 24))

// device-coherent (bypass L1+L2) wide ops
__device__ __forceinline__ void store_coh_x4(void* p, u32x4 d) {
    asm volatile("global_store_dwordx4 %0, %1, off sc0 sc1" ::"v"(p), "v"(d) : "memory");
}
__device__ __forceinline__ void load_coh_2x4(const void* p0, const void* p1, u32x4& a, u32x4& b) {
    asm volatile(
        "global_load_dwordx4 %0, %2, off sc0 sc1\n\t"
        "global_load_dwordx4 %1, %3, off sc0 sc1\n\t"
        "s_waitcnt vmcnt(0)"
        : "=v"(a), "=v"(b)
        : "v"(p0), "v"(p1)
        : "memory");
}

// ---------- kernel 1: persistent stacked-LSTM scan ----------
// 256 blocks x 512 threads (8 waves), 1 block/CU.
// __launch_bounds__(512, 2): an 8-wave block needs 2 waves/EU; this pins the VGPR
// cap at 256/wave so the workgroup is guaranteed schedulable (8 x 256 VGPR = full CU).
// Block b owns units {4b..4b+3}. Wave wid: u = wid&3, half = wid>>2.
// Waves 0-3 compute layers 0-3 for units 0-3; waves 4-7 compute layers 4-7.
// This halves per-wave weight registers (wh: 128 VGPRs instead of 256) so nothing
// spills under the 256-VGPR cap (the 4-wave version spilled ~100 regs to scratch
// and re-loaded them in the hot loop every step).
// Cell state c for unit u hands off between wave u and wave 4+u via c_xfer[u] in LDS,
// ordered by the barriers that already exist in the protocol.
// Precision: h-weights = packed bf16 pairs in regs + int8 residual (scale 2^-20) in
// LDS (128 KiB) -> effective weight error <= 2^-21. x-weights exact fp32 in regs.
// Broadcast: per-consumer-group mailbox replicas. Chunk = 4 x {fp32 h, u32 tag} = 32B.
// mail layout: [(copy*2 + parity)*256 + producer] * 32 bytes.
// Protocol safety: producer can't publish step s+2 (which overwrites slot parity of s)
// before completing its poll of s+1, which requires ALL blocks to have pushed s+1,
// which requires them to have consumed s. So no pending tag is ever overwritten.
__global__ void __launch_bounds__(512, 2)
lstm_persistent(const float* __restrict__ website, const float* __restrict__ payload,
                const float* __restrict__ W_ih, const float* __restrict__ W_hh,
                const float* __restrict__ b_ih, const float* __restrict__ b_hh,
                char* mail, float* c_out, int ncopies) {
    __shared__ float h_lds[HID];
    __shared__ float h_new[4];
    __shared__ float c_xfer[4];
    extern __shared__ __align__(16) uint8_t res_lds[];  // 4*8*4*64*16 = 128 KiB

    const int tid = threadIdx.x;    // 0..511
    const int b = blockIdx.x;       // 0..255
    const int wid = tid >> 6;       // wave 0..7
    const int u = wid & 3;          // unit within block
    const int half = wid >> 2;      // 0: layers 0-3, 1: layers 4-7
    const int lane = tid & 63;
    const int k = b * 4 + u;        // global hidden unit
    const int rcopy = b & (ncopies - 1);

    // ---- one-time: pack THIS WAVE'S 4 layers (bf16 hi in regs, int8 residual in LDS) ----
    uint32_t wh[4][4][8];  // [local layer][gate][pair p] -> cols (2L+128p, 2L+128p+1)
    float wxf[4][4][2];    // exact fp32 x-weights (cols 2L, 2L+1), zero for lanes >= 50
    float bias[4][4];
#pragma unroll
    for (int ll = 0; ll < 4; ++ll) {
        const int L = half * 4 + ll;  // global layer
#pragma unroll
        for (int g = 0; g < 4; ++g) {
            const int row = 1024 * g + k;
            const float* src = W_hh + ((size_t)(L * 4096 + row)) * 1024;
            uint32_t rb[4];
#pragma unroll
            for (int p = 0; p < 8; ++p) {
                const int c0 = 2 * lane + 128 * p;
                const float w0 = src[c0], w1 = src[c0 + 1];
                const uint32_t pk = f2bf(w0) | (f2bf(w1) << 16);
                wh[ll][g][p] = pk;
                // residual, quantized at scale 2^-20 (max |r| = 6.1e-5 < 127*2^-20)
                const float r0 = (w0 - bflo(pk)) * 1048576.0f;
                const float r1 = (w1 - bfhi(pk)) * 1048576.0f;
                const int i0 = __float2int_rn(fminf(fmaxf(r0, -127.0f), 127.0f));
                const int i1 = __float2int_rn(fminf(fmaxf(r1, -127.0f), 127.0f));
                const uint32_t byt = ((uint32_t)i0 & 0xFFu) | (((uint32_t)i1 & 0xFFu) << 8);
                if ((p & 1) == 0) rb[p >> 1] = byt;
                else rb[p >> 1] |= (byt << 16);
            }
            {
                u32x4 v;
                v.x = rb[0]; v.y = rb[1]; v.z = rb[2]; v.w = rb[3];
                u32x4* dst = (u32x4*)res_lds + (((u * NLAYERS + L) * 4 + g) * 64 + lane);
                *dst = v;
            }
            if (lane < 50) {
                const float* sx = W_ih + ((size_t)(L * 4096 + row)) * NLET + 2 * lane;
                wxf[ll][g][0] = sx[0];
                wxf[ll][g][1] = sx[1];
            } else {
                wxf[ll][g][0] = 0.f;
                wxf[ll][g][1] = 0.f;
            }
            bias[ll][g] = b_ih[L * 4096 + row] + b_hh[L * 4096 + row];
        }
    }

    // init h(0)=0, c(0)=0
    if (tid < 256) ((float4*)h_lds)[tid] = make_float4(0.f, 0.f, 0.f, 0.f);
    if (tid < 4) { h_new[tid] = 0.f; c_xfer[tid] = 0.f; }
    float c = 0.0f;
    __syncthreads();

    for (int t = 0; t < T_TOTAL; ++t) {
        // x for this timestep (shared by all 8 layers)
        float x0 = 0.f, x1 = 0.f;
        if (lane < 50) {
            const float* xp = (t < 2048) ? (website + (size_t)t * NLET)
                                         : (payload + (size_t)(t - 2048) * NLET);
            x0 = xp[2 * lane];
            x1 = xp[2 * lane + 1];
        }
#pragma unroll
        for (int l = 0; l < NLAYERS; ++l) {
            const int s = t * NLAYERS + l + 1;  // step being produced (1..32768)
            const int par = s & 1;
            const int ll = l & 3;
            const bool mine = ((l >> 2) == half);  // wave-uniform

            if (mine) {
                // pick up cell state at the start of this wave's half
                if (ll == 0) c = c_xfer[u];

                // ---- load h fragment + residual bytes (same-thread RAW on res_lds) ----
                float2 hv[8];
#pragma unroll
                for (int p = 0; p < 8; ++p)
                    hv[p] = *(const float2*)&h_lds[2 * lane + 128 * p];
                const u32x4* rr = (const u32x4*)res_lds + ((u * NLAYERS + l) * 4) * 64 + lane;
                const u32x4 rg0 = rr[0];
                const u32x4 rg1 = rr[64];
                const u32x4 rg2 = rr[128];
                const u32x4 rg3 = rr[192];

                // ---- bf16 hi-part dot products ----
                float acc0 = 0.f, acc1 = 0.f, acc2 = 0.f, acc3 = 0.f;
#pragma unroll
                for (int p = 0; p < 8; ++p) {
                    const float hA = hv[p].x, hB = hv[p].y;
                    uint32_t w;
                    w = wh[ll][0][p]; acc0 = fmaf(bflo(w), hA, acc0); acc0 = fmaf(bfhi(w), hB, acc0);
                    w = wh[ll][1][p]; acc1 = fmaf(bflo(w), hA, acc1); acc1 = fmaf(bfhi(w), hB, acc1);
                    w = wh[ll][2][p]; acc2 = fmaf(bflo(w), hA, acc2); acc2 = fmaf(bfhi(w), hB, acc2);
                    w = wh[ll][3][p]; acc3 = fmaf(bflo(w), hA, acc3); acc3 = fmaf(bfhi(w), hB, acc3);
                }
                // ---- int8 residual correction (scale 2^-20) ----
                float ra0 = 0.f, ra1 = 0.f, ra2 = 0.f, ra3 = 0.f;
#pragma unroll
                for (int p = 0; p < 8; ++p) {
                    const float hA = hv[p].x, hB = hv[p].y;
                    const int b0 = 2 * (p & 1), b1 = 2 * (p & 1) + 1;
                    uint32_t w;
                    w = rg0[p >> 1]; ra0 = fmaf(SBYTE(w, b0), hA, ra0); ra0 = fmaf(SBYTE(w, b1), hB, ra0);
                    w = rg1[p >> 1]; ra1 = fmaf(SBYTE(w, b0), hA, ra1); ra1 = fmaf(SBYTE(w, b1), hB, ra1);
                    w = rg2[p >> 1]; ra2 = fmaf(SBYTE(w, b0), hA, ra2); ra2 = fmaf(SBYTE(w, b1), hB, ra2);
                    w = rg3[p >> 1]; ra3 = fmaf(SBYTE(w, b0), hA, ra3); ra3 = fmaf(SBYTE(w, b1), hB, ra3);
                }
                acc0 = fmaf(ra0, 0x1.0p-20f, acc0);
                acc1 = fmaf(ra1, 0x1.0p-20f, acc1);
                acc2 = fmaf(ra2, 0x1.0p-20f, acc2);
                acc3 = fmaf(ra3, 0x1.0p-20f, acc3);
                // ---- exact fp32 x contribution ----
                acc0 = fmaf(wxf[ll][0][0], x0, acc0); acc0 = fmaf(wxf[ll][0][1], x1, acc0);
                acc1 = fmaf(wxf[ll][1][0], x0, acc1); acc1 = fmaf(wxf[ll][1][1], x1, acc1);
                acc2 = fmaf(wxf[ll][2][0], x0, acc2); acc2 = fmaf(wxf[ll][2][1], x1, acc2);
                acc3 = fmaf(wxf[ll][3][0], x0, acc3); acc3 = fmaf(wxf[ll][3][1], x1, acc3);

#pragma unroll
                for (int mm = 32; mm > 0; mm >>= 1) {
                    acc0 += __shfl_xor(acc0, mm, 64);
                    acc1 += __shfl_xor(acc1, mm, 64);
                    acc2 += __shfl_xor(acc2, mm, 64);
                    acc3 += __shfl_xor(acc3, mm, 64);
                }
                const float gi = sigm(acc0 + bias[ll][0]);
                const float gf = sigm(acc1 + bias[ll][1]);
                const float gg = tanh_f(acc2 + bias[ll][2]);
                const float go = sigm(acc3 + bias[ll][3]);
                c = fmaf(gf, c, gi * gg);
                const float hn = go * tanh_f(c);
                if (lane == 0) {
                    h_new[u] = hn;
                    if (ll == 3) c_xfer[u] = c;  // hand off to the other half / next t
                }
            }
            __syncthreads();  // h_new (+ c_xfer) ready; everyone done reading h_lds

            // ---- push: store this block's 32B chunk to every mailbox copy ----
            const float f0 = h_new[0], f1 = h_new[1], f2 = h_new[2], f3 = h_new[3];
            if (tid < ncopies) {
                char* dst = mail + ((size_t)((tid * 2 + par) * 256 + b)) * 32;
                u32x4 d0, d1;
                d0.x = __float_as_uint(f0); d0.y = (uint32_t)s;
                d0.z = __float_as_uint(f1); d0.w = (uint32_t)s;
                d1.x = __float_as_uint(f2); d1.y = (uint32_t)s;
                d1.z = __float_as_uint(f3); d1.w = (uint32_t)s;
                store_coh_x4(dst, d0);
                store_coh_x4(dst + 16, d1);
            }

            // ---- poll: thread t (<256) collects producer t's chunk from our copy ----
            if (tid < 256) {
                const char* srcp = mail + ((size_t)((rcopy * 2 + par) * 256 + tid)) * 32;
                u32x4 a0, a1;
                for (;;) {
                    load_coh_2x4(srcp, srcp + 16, a0, a1);
                    if (a0.y == (uint32_t)s && a0.w == (uint32_t)s &&
                        a1.y == (uint32_t)s && a1.w == (uint32_t)s)
                        break;
                    __builtin_amdgcn_s_sleep(2);
                }
                h_lds[4 * tid + 0] = __uint_as_float(a0.x);
                h_lds[4 * tid + 1] = __uint_as_float(a0.z);
                h_lds[4 * tid + 2] = __uint_as_float(a1.x);
                h_lds[4 * tid + 3] = __uint_as_float(a1.z);
            }
            __syncthreads();  // h_lds now holds h(s)
        }
    }

    // final c lives in the half-1 waves (after layer 7 of t=4095)
    if (half == 1 && lane == 0) c_out[k] = c;
}

// ---------- kernel 2: head — out = sigmoid(W_out @ (W_lin@c + b_lin) + b_out) ----------
__global__ void head_kernel(const float* __restrict__ c_out, const float* __restrict__ W_lin,
                            const float* __restrict__ b_lin, const float* __restrict__ W_out,
                            const float* __restrict__ b_out, float* out) {
    const int lane = threadIdx.x;  // 64 threads, one wave
    float cv[16];
    const float4* cp = (const float4*)(c_out + lane * 16);
#pragma unroll
    for (int q = 0; q < 4; ++q) {
        float4 v = cp[q];
        cv[4 * q + 0] = v.x;
        cv[4 * q + 1] = v.y;
        cv[4 * q + 2] = v.z;
        cv[4 * q + 3] = v.w;
    }
    float fsum = 0.f;
#pragma unroll
    for (int i = 0; i < 16; ++i) {
        const float* w = W_lin + (size_t)i * HID + lane * 16;
        float a = 0.f;
#pragma unroll
        for (int m = 0; m < 16; ++m) a = fmaf(w[m], cv[m], a);
#pragma unroll
        for (int mm = 32; mm > 0; mm >>= 1) a += __shfl_xor(a, mm, 64);
        fsum = fmaf(W_out[i], a + b_lin[i], fsum);
    }
    if (lane == 0) out[0] = sigm(fsum + b_out[0]);
}

extern "C" void kernel_launch(void* const* d_in, const int* in_sizes, int n_in, void* d_out,
                              int out_size, void* d_ws, size_t ws_size, hipStream_t stream) {
    (void)in_sizes; (void)n_in; (void)out_size;
    const float* website = (const float*)d_in[0];
    const float* payload = (const float*)d_in[1];
    const float* W_ih = (const float*)d_in[2];
    const float* W_hh = (const float*)d_in[3];
    const float* b_ih = (const float*)d_in[4];
    const float* b_hh = (const float*)d_in[5];
    const float* W_lin = (const float*)d_in[6];
    const float* b_lin = (const float*)d_in[7];
    const float* W_out = (const float*)d_in[8];
    const float* b_out = (const float*)d_in[9];

    // mailbox replicas: ncopies * 2(par) * 256(producers) * 32B = ncopies * 16 KiB
    int ncopies = 64;
    while (ncopies > 1 && (size_t)ncopies * 16384 + 4096 > ws_size) ncopies >>= 1;
    char* mail = (char*)d_ws;
    float* c_out = (float*)((char*)d_ws + (size_t)ncopies * 16384);

    hipMemsetAsync(mail, 0, (size_t)ncopies * 16384, stream);  // zero tags (s starts at 1)
    // 128 KiB dynamic LDS for int8 weight residuals (gfx950: 160 KiB/CU available)
    lstm_persistent<<<256, 512, 131072, stream>>>(website, payload, W_ih, W_hh, b_ih, b_hh,
                                                  mail, c_out, ncopies);
    head_kernel<<<1, 64, 0, stream>>>(c_out, W_lin, b_lin, W_out, b_out, (float*)d_out);
}

// Round 4
// 283532.495 us; speedup vs baseline: 1.3055x; 1.3055x over previous
//
#include <hip/hip_runtime.h>
#include <stdint.h>

#define HID 1024
#define NLAYERS 8
#define NLET 100
#define T_TOTAL 4096

typedef uint32_t u32x4 __attribute__((ext_vector_type(4)));

// ---------- helpers ----------
__device__ __forceinline__ uint32_t f2bf(float f) {
    uint32_t u = __float_as_uint(f);
    return (u + 0x7FFFu + ((u >> 16) & 1u)) >> 16;
}
__device__ __forceinline__ float bflo(uint32_t p) { return __uint_as_float(p << 16); }
__device__ __forceinline__ float bfhi(uint32_t p) { return __uint_as_float(p & 0xFFFF0000u); }
__device__ __forceinline__ float sigm(float x) { return 1.0f / (1.0f + __expf(-x)); }
__device__ __forceinline__ float tanh_f(float x) {
    float xx = fminf(fmaxf(x, -15.0f), 15.0f);
    float e = __expf(2.0f * xx);
    return (e - 1.0f) / (e + 1.0f);
}
// signed byte b (0..3) of word w, as float
#define SBYTE(w, b) ((float)((int)((w) << (24 - 8 * (b))) >> 24))
// round fp32 bit pattern to 24-bit (drop low 8 mantissa bits, round-half-up).
// |h|<1 (tanh-bounded) so the +0x80 carry stays inside the same sign monotone range.
__device__ __forceinline__ uint32_t rnd24(float f) {
    return (__float_as_uint(f) + 0x80u) >> 8;
}

// device-coherent (bypass L1+L2) wide ops
__device__ __forceinline__ void store_coh_x4(void* p, u32x4 d) {
    asm volatile("global_store_dwordx4 %0, %1, off sc0 sc1" ::"v"(p), "v"(d) : "memory");
}
__device__ __forceinline__ void load_coh_x4(const void* p, u32x4& a) {
    asm volatile(
        "global_load_dwordx4 %0, %1, off sc0 sc1\n\t"
        "s_waitcnt vmcnt(0)"
        : "=v"(a)
        : "v"(p)
        : "memory");
}

// ---------- kernel 1: persistent stacked-LSTM scan ----------
// 256 blocks x 256 threads (4 waves), 1 block/CU. Block b owns units {4b..4b+3};
// wave u owns unit k=4b+u for ALL 8 layers. (4-wave shape = best measured; its
// register overflow spills to AGPRs -- round-1 FETCH matched mailbox traffic exactly,
// i.e. no scratch HBM traffic. The 8-wave variant spilled to scratch and regressed.)
// Precision: h-weights = packed bf16 pairs in regs + int8 residual (scale 2^-20) in
// LDS (128 KiB) -> effective weight error <= 2^-21. x-weights exact fp32 in regs.
// Mailbox (traffic-halved vs 32-B chunks): 16-B self-contained chunk per producer:
//   w0 = (t0<<8)|(t1>>16), w1 = (t1<<16)|(t2>>8), w2 = (t2<<24)|t3, w3 = step tag
// where t_i = 24-bit-rounded h of unit 4b+i. One dwordx4 store / one dwordx4 poll.
// h error from 24-bit transit: 2^-17 relative (256x finer than bf16; absmax was 0.0).
// mail layout: [(copy*2 + parity)*256 + producer] * 16 bytes.
// Protocol safety: producer can't publish s+2 (same parity slot as s) before
// completing its poll of s+1, which requires ALL blocks to have pushed s+1, which
// requires them to have consumed s (the consume IS the tagged 16-B load). So no
// pending chunk is ever overwritten.
__global__ void __launch_bounds__(256, 1)
lstm_persistent(const float* __restrict__ website, const float* __restrict__ payload,
                const float* __restrict__ W_ih, const float* __restrict__ W_hh,
                const float* __restrict__ b_ih, const float* __restrict__ b_hh,
                char* mail, float* c_out, int ncopies) {
    __shared__ float h_lds[HID];
    __shared__ float h_new[4];
    extern __shared__ __align__(16) uint8_t res_lds[];  // 4*8*4*64*16 = 128 KiB

    const int tid = threadIdx.x;    // 0..255
    const int b = blockIdx.x;       // 0..255
    const int u = tid >> 6;         // wave 0..3 = unit within block
    const int lane = tid & 63;
    const int k = b * 4 + u;        // global hidden unit
    const int rcopy = b & (ncopies - 1);

    // ---- one-time: pack weights (bf16 hi in regs, int8 residual in LDS) ----
    uint32_t wh[NLAYERS][4][8];  // [layer][gate][pair p] -> cols (2L+128p, 2L+128p+1)
    float wxf[NLAYERS][4][2];    // exact fp32 x-weights (cols 2L, 2L+1), zero for lanes >= 50
    float bias[NLAYERS][4];
#pragma unroll
    for (int l = 0; l < NLAYERS; ++l) {
#pragma unroll
        for (int g = 0; g < 4; ++g) {
            const int row = 1024 * g + k;
            const float* src = W_hh + ((size_t)(l * 4096 + row)) * 1024;
            uint32_t rb[4];
#pragma unroll
            for (int p = 0; p < 8; ++p) {
                const int c0 = 2 * lane + 128 * p;
                const float w0 = src[c0], w1 = src[c0 + 1];
                const uint32_t pk = f2bf(w0) | (f2bf(w1) << 16);
                wh[l][g][p] = pk;
                // residual, quantized at scale 2^-20 (max |r| = 6.1e-5 < 127*2^-20)
                const float r0 = (w0 - bflo(pk)) * 1048576.0f;
                const float r1 = (w1 - bfhi(pk)) * 1048576.0f;
                const int i0 = __float2int_rn(fminf(fmaxf(r0, -127.0f), 127.0f));
                const int i1 = __float2int_rn(fminf(fmaxf(r1, -127.0f), 127.0f));
                const uint32_t byt = ((uint32_t)i0 & 0xFFu) | (((uint32_t)i1 & 0xFFu) << 8);
                if ((p & 1) == 0) rb[p >> 1] = byt;
                else rb[p >> 1] |= (byt << 16);
            }
            {
                u32x4 v;
                v.x = rb[0]; v.y = rb[1]; v.z = rb[2]; v.w = rb[3];
                u32x4* dst = (u32x4*)res_lds + (((u * NLAYERS + l) * 4 + g) * 64 + lane);
                *dst = v;
            }
            if (lane < 50) {
                const float* sx = W_ih + ((size_t)(l * 4096 + row)) * NLET + 2 * lane;
                wxf[l][g][0] = sx[0];
                wxf[l][g][1] = sx[1];
            } else {
                wxf[l][g][0] = 0.f;
                wxf[l][g][1] = 0.f;
            }
            bias[l][g] = b_ih[l * 4096 + row] + b_hh[l * 4096 + row];
        }
    }

    // init h(0)=0, c(0)=0
    ((float4*)h_lds)[tid] = make_float4(0.f, 0.f, 0.f, 0.f);
    float c = 0.0f;
    __syncthreads();

    for (int t = 0; t < T_TOTAL; ++t) {
        // x for this timestep (shared by all 8 layers)
        float x0 = 0.f, x1 = 0.f;
        if (lane < 50) {
            const float* xp = (t < 2048) ? (website + (size_t)t * NLET)
                                         : (payload + (size_t)(t - 2048) * NLET);
            x0 = xp[2 * lane];
            x1 = xp[2 * lane + 1];
        }
#pragma unroll
        for (int l = 0; l < NLAYERS; ++l) {
            const int s = t * NLAYERS + l + 1;  // step being produced (1..32768)
            const int par = s & 1;

            // ---- compute this wave's unit: 4 gate dot-products over h + x ----
            float2 hv[8];
#pragma unroll
            for (int p = 0; p < 8; ++p)
                hv[p] = *(const float2*)&h_lds[2 * lane + 128 * p];
            const u32x4* rr = (const u32x4*)res_lds + ((u * NLAYERS + l) * 4) * 64 + lane;
            const u32x4 rg0 = rr[0];
            const u32x4 rg1 = rr[64];
            const u32x4 rg2 = rr[128];
            const u32x4 rg3 = rr[192];

            // ---- bf16 hi-part dot products ----
            float acc0 = 0.f, acc1 = 0.f, acc2 = 0.f, acc3 = 0.f;
#pragma unroll
            for (int p = 0; p < 8; ++p) {
                const float hA = hv[p].x, hB = hv[p].y;
                uint32_t w;
                w = wh[l][0][p]; acc0 = fmaf(bflo(w), hA, acc0); acc0 = fmaf(bfhi(w), hB, acc0);
                w = wh[l][1][p]; acc1 = fmaf(bflo(w), hA, acc1); acc1 = fmaf(bfhi(w), hB, acc1);
                w = wh[l][2][p]; acc2 = fmaf(bflo(w), hA, acc2); acc2 = fmaf(bfhi(w), hB, acc2);
                w = wh[l][3][p]; acc3 = fmaf(bflo(w), hA, acc3); acc3 = fmaf(bfhi(w), hB, acc3);
            }
            // ---- int8 residual correction (scale 2^-20) ----
            float ra0 = 0.f, ra1 = 0.f, ra2 = 0.f, ra3 = 0.f;
#pragma unroll
            for (int p = 0; p < 8; ++p) {
                const float hA = hv[p].x, hB = hv[p].y;
                const int b0 = 2 * (p & 1), b1 = 2 * (p & 1) + 1;
                uint32_t w;
                w = rg0[p >> 1]; ra0 = fmaf(SBYTE(w, b0), hA, ra0); ra0 = fmaf(SBYTE(w, b1), hB, ra0);
                w = rg1[p >> 1]; ra1 = fmaf(SBYTE(w, b0), hA, ra1); ra1 = fmaf(SBYTE(w, b1), hB, ra1);
                w = rg2[p >> 1]; ra2 = fmaf(SBYTE(w, b0), hA, ra2); ra2 = fmaf(SBYTE(w, b1), hB, ra2);
                w = rg3[p >> 1]; ra3 = fmaf(SBYTE(w, b0), hA, ra3); ra3 = fmaf(SBYTE(w, b1), hB, ra3);
            }
            acc0 = fmaf(ra0, 0x1.0p-20f, acc0);
            acc1 = fmaf(ra1, 0x1.0p-20f, acc1);
            acc2 = fmaf(ra2, 0x1.0p-20f, acc2);
            acc3 = fmaf(ra3, 0x1.0p-20f, acc3);
            // ---- exact fp32 x contribution ----
            acc0 = fmaf(wxf[l][0][0], x0, acc0); acc0 = fmaf(wxf[l][0][1], x1, acc0);
            acc1 = fmaf(wxf[l][1][0], x0, acc1); acc1 = fmaf(wxf[l][1][1], x1, acc1);
            acc2 = fmaf(wxf[l][2][0], x0, acc2); acc2 = fmaf(wxf[l][2][1], x1, acc2);
            acc3 = fmaf(wxf[l][3][0], x0, acc3); acc3 = fmaf(wxf[l][3][1], x1, acc3);

#pragma unroll
            for (int mm = 32; mm > 0; mm >>= 1) {
                acc0 += __shfl_xor(acc0, mm, 64);
                acc1 += __shfl_xor(acc1, mm, 64);
                acc2 += __shfl_xor(acc2, mm, 64);
                acc3 += __shfl_xor(acc3, mm, 64);
            }
            const float gi = sigm(acc0 + bias[l][0]);
            const float gf = sigm(acc1 + bias[l][1]);
            const float gg = tanh_f(acc2 + bias[l][2]);
            const float go = sigm(acc3 + bias[l][3]);
            c = fmaf(gf, c, gi * gg);
            const float hn = go * tanh_f(c);
            if (lane == 0) h_new[u] = hn;
            __syncthreads();  // h_new ready; everyone done reading h_lds

            // ---- push: pack 4x24-bit h + tag into ONE 16-B chunk, store to each copy ----
            if (tid < ncopies) {
                const uint32_t t0 = rnd24(h_new[0]);
                const uint32_t t1 = rnd24(h_new[1]);
                const uint32_t t2 = rnd24(h_new[2]);
                const uint32_t t3 = rnd24(h_new[3]);
                u32x4 d;
                d.x = (t0 << 8) | (t1 >> 16);
                d.y = (t1 << 16) | (t2 >> 8);
                d.z = (t2 << 24) | t3;
                d.w = (uint32_t)s;
                char* dst = mail + ((size_t)((tid * 2 + par) * 256 + b)) * 16;
                store_coh_x4(dst, d);
            }

            // ---- poll: thread t collects producer t's 16-B chunk from our copy ----
            {
                const char* srcp = mail + ((size_t)((rcopy * 2 + par) * 256 + tid)) * 16;
                u32x4 a;
                for (;;) {
                    load_coh_x4(srcp, a);
                    if (a.w == (uint32_t)s) break;
                    __builtin_amdgcn_s_sleep(2);
                }
                h_lds[4 * tid + 0] = __uint_as_float(a.x & 0xFFFFFF00u);
                h_lds[4 * tid + 1] = __uint_as_float(((a.x & 0xFFu) << 24) | ((a.y >> 16) << 8));
                h_lds[4 * tid + 2] = __uint_as_float(((a.y & 0xFFFFu) << 16) | ((a.z >> 24) << 8));
                h_lds[4 * tid + 3] = __uint_as_float((a.z & 0xFFFFFFu) << 8);
            }
            __syncthreads();  // h_lds now holds h(s)
        }
    }

    if (lane == 0) c_out[k] = c;
}

// ---------- kernel 2: head — out = sigmoid(W_out @ (W_lin@c + b_lin) + b_out) ----------
__global__ void head_kernel(const float* __restrict__ c_out, const float* __restrict__ W_lin,
                            const float* __restrict__ b_lin, const float* __restrict__ W_out,
                            const float* __restrict__ b_out, float* out) {
    const int lane = threadIdx.x;  // 64 threads, one wave
    float cv[16];
    const float4* cp = (const float4*)(c_out + lane * 16);
#pragma unroll
    for (int q = 0; q < 4; ++q) {
        float4 v = cp[q];
        cv[4 * q + 0] = v.x;
        cv[4 * q + 1] = v.y;
        cv[4 * q + 2] = v.z;
        cv[4 * q + 3] = v.w;
    }
    float fsum = 0.f;
#pragma unroll
    for (int i = 0; i < 16; ++i) {
        const float* w = W_lin + (size_t)i * HID + lane * 16;
        float a = 0.f;
#pragma unroll
        for (int m = 0; m < 16; ++m) a = fmaf(w[m], cv[m], a);
#pragma unroll
        for (int mm = 32; mm > 0; mm >>= 1) a += __shfl_xor(a, mm, 64);
        fsum = fmaf(W_out[i], a + b_lin[i], fsum);
    }
    if (lane == 0) out[0] = sigm(fsum + b_out[0]);
}

extern "C" void kernel_launch(void* const* d_in, const int* in_sizes, int n_in, void* d_out,
                              int out_size, void* d_ws, size_t ws_size, hipStream_t stream) {
    (void)in_sizes; (void)n_in; (void)out_size;
    const float* website = (const float*)d_in[0];
    const float* payload = (const float*)d_in[1];
    const float* W_ih = (const float*)d_in[2];
    const float* W_hh = (const float*)d_in[3];
    const float* b_ih = (const float*)d_in[4];
    const float* b_hh = (const float*)d_in[5];
    const float* W_lin = (const float*)d_in[6];
    const float* b_lin = (const float*)d_in[7];
    const float* W_out = (const float*)d_in[8];
    const float* b_out = (const float*)d_in[9];

    // mailbox replicas: ncopies * 2(par) * 256(producers) * 16B = ncopies * 8 KiB
    int ncopies = 64;
    while (ncopies > 1 && (size_t)ncopies * 8192 + 4096 > ws_size) ncopies >>= 1;
    char* mail = (char*)d_ws;
    float* c_out = (float*)((char*)d_ws + (size_t)ncopies * 8192);

    hipMemsetAsync(mail, 0, (size_t)ncopies * 8192, stream);  // zero tags (s starts at 1)
    // 128 KiB dynamic LDS for int8 weight residuals (gfx950: 160 KiB/CU available)
    lstm_persistent<<<256, 256, 131072, stream>>>(website, payload, W_ih, W_hh, b_ih, b_hh,
                                                  mail, c_out, ncopies);
    head_kernel<<<1, 64, 0, stream>>>(c_out, W_lin, b_lin, W_out, b_out, (float*)d_out);
}

// Round 5
// 283518.237 us; speedup vs baseline: 1.3055x; 1.0001x over previous
//
#include <hip/hip_runtime.h>
#include <stdint.h>

#define HID 1024
#define NLAYERS 8
#define NLET 100
#define T_TOTAL 4096

typedef uint32_t u32x4 __attribute__((ext_vector_type(4)));

// ---------- helpers ----------
__device__ __forceinline__ uint32_t f2bf(float f) {
    uint32_t u = __float_as_uint(f);
    return (u + 0x7FFFu + ((u >> 16) & 1u)) >> 16;
}
__device__ __forceinline__ float bflo(uint32_t p) { return __uint_as_float(p << 16); }
__device__ __forceinline__ float bfhi(uint32_t p) { return __uint_as_float(p & 0xFFFF0000u); }
__device__ __forceinline__ float sigm(float x) { return 1.0f / (1.0f + __expf(-x)); }
__device__ __forceinline__ float tanh_f(float x) {
    float xx = fminf(fmaxf(x, -15.0f), 15.0f);
    float e = __expf(2.0f * xx);
    return (e - 1.0f) / (e + 1.0f);
}
// signed byte b (0..3) of word w, as float
#define SBYTE(w, b) ((float)((int)((w) << (24 - 8 * (b))) >> 24))
// round fp32 bit pattern to 24-bit (drop low 8 mantissa bits, round-half-up).
// |h|<1 (tanh-bounded) so the +0x80 carry stays inside the same sign monotone range.
__device__ __forceinline__ uint32_t rnd24(float f) {
    return (__float_as_uint(f) + 0x80u) >> 8;
}

// device-coherent (bypass L1+L2) wide ops
__device__ __forceinline__ void store_coh_x4(void* p, u32x4 d) {
    asm volatile("global_store_dwordx4 %0, %1, off sc0 sc1" ::"v"(p), "v"(d) : "memory");
}
__device__ __forceinline__ void load_coh_x4(const void* p, u32x4& a) {
    asm volatile(
        "global_load_dwordx4 %0, %1, off sc0 sc1\n\t"
        "s_waitcnt vmcnt(0)"
        : "=v"(a)
        : "v"(p)
        : "memory");
}

// ---------- kernel 1: persistent stacked-LSTM scan ----------
// 256 blocks x 256 threads (4 waves), 1 block/CU. Block b owns units {4b..4b+3};
// wave u owns unit k=4b+u for ALL 8 layers. (4-wave shape = best measured; its
// register overflow spills to AGPRs -- FETCH matches mailbox traffic exactly, i.e.
// no scratch HBM traffic. The 8-wave variant spilled to scratch and regressed.)
// Precision: h-weights = packed bf16 pairs in regs + int8 residual (scale 2^-20) in
// LDS (128 KiB) -> effective weight error <= 2^-21. x-weights exact fp32 in regs.
// Mailbox: 16-B self-contained chunk per producer (4 x 24-bit h + 32-bit step tag).
// mail layout: [(copy*2 + parity)*256 + producer] * 16 bytes.
//
// R1/R4 evidence: step time tracks the device-wide count of sc0/sc1 transactions at
// ~24-25 GT/s (R1: 281K trans / 11.05us; R4: 222K / 9.3us). Polls that fire before
// data is ready burn full-rate loads that queue behind everyone else's. So: PACED
// POLLING -- adaptive pre-sleep between the push and the first poll so the first
// load usually hits. Sleeping never blocks progress; protocol unchanged.
// Protocol safety: producer can't publish s+2 (same parity slot as s) before
// completing its poll of s+1, which requires ALL blocks to have pushed s+1, which
// requires them to have consumed s. So no pending chunk is ever overwritten.
__global__ void __launch_bounds__(256, 1)
lstm_persistent(const float* __restrict__ website, const float* __restrict__ payload,
                const float* __restrict__ W_ih, const float* __restrict__ W_hh,
                const float* __restrict__ b_ih, const float* __restrict__ b_hh,
                char* mail, float* c_out, int ncopies) {
    __shared__ float h_lds[HID];
    __shared__ float h_new[4];
    extern __shared__ __align__(16) uint8_t res_lds[];  // 4*8*4*64*16 = 128 KiB

    const int tid = threadIdx.x;    // 0..255
    const int b = blockIdx.x;       // 0..255
    const int u = tid >> 6;         // wave 0..3 = unit within block
    const int lane = tid & 63;
    const int k = b * 4 + u;        // global hidden unit
    const int rcopy = b & (ncopies - 1);

    // ---- one-time: pack weights (bf16 hi in regs, int8 residual in LDS) ----
    uint32_t wh[NLAYERS][4][8];  // [layer][gate][pair p] -> cols (2L+128p, 2L+128p+1)
    float wxf[NLAYERS][4][2];    // exact fp32 x-weights (cols 2L, 2L+1), zero for lanes >= 50
    float bias[NLAYERS][4];
#pragma unroll
    for (int l = 0; l < NLAYERS; ++l) {
#pragma unroll
        for (int g = 0; g < 4; ++g) {
            const int row = 1024 * g + k;
            const float* src = W_hh + ((size_t)(l * 4096 + row)) * 1024;
            uint32_t rb[4];
#pragma unroll
            for (int p = 0; p < 8; ++p) {
                const int c0 = 2 * lane + 128 * p;
                const float w0 = src[c0], w1 = src[c0 + 1];
                const uint32_t pk = f2bf(w0) | (f2bf(w1) << 16);
                wh[l][g][p] = pk;
                // residual, quantized at scale 2^-20 (max |r| = 6.1e-5 < 127*2^-20)
                const float r0 = (w0 - bflo(pk)) * 1048576.0f;
                const float r1 = (w1 - bfhi(pk)) * 1048576.0f;
                const int i0 = __float2int_rn(fminf(fmaxf(r0, -127.0f), 127.0f));
                const int i1 = __float2int_rn(fminf(fmaxf(r1, -127.0f), 127.0f));
                const uint32_t byt = ((uint32_t)i0 & 0xFFu) | (((uint32_t)i1 & 0xFFu) << 8);
                if ((p & 1) == 0) rb[p >> 1] = byt;
                else rb[p >> 1] |= (byt << 16);
            }
            {
                u32x4 v;
                v.x = rb[0]; v.y = rb[1]; v.z = rb[2]; v.w = rb[3];
                u32x4* dst = (u32x4*)res_lds + (((u * NLAYERS + l) * 4 + g) * 64 + lane);
                *dst = v;
            }
            if (lane < 50) {
                const float* sx = W_ih + ((size_t)(l * 4096 + row)) * NLET + 2 * lane;
                wxf[l][g][0] = sx[0];
                wxf[l][g][1] = sx[1];
            } else {
                wxf[l][g][0] = 0.f;
                wxf[l][g][1] = 0.f;
            }
            bias[l][g] = b_ih[l * 4096 + row] + b_hh[l * 4096 + row];
        }
    }

    // init h(0)=0, c(0)=0
    ((float4*)h_lds)[tid] = make_float4(0.f, 0.f, 0.f, 0.f);
    float c = 0.0f;
    // adaptive poll delay, units of s_sleep(8) ~= 512 cycles ~= 0.24us.
    // s_sleep is wave-granular: the wave sleeps for max(dl) across lanes, and that
    // max lane's adaptation governs (hit -> -1, miss -> +retries), self-regulating.
    int dl = 6;
    __syncthreads();

    for (int t = 0; t < T_TOTAL; ++t) {
        // x for this timestep (shared by all 8 layers)
        float x0 = 0.f, x1 = 0.f;
        if (lane < 50) {
            const float* xp = (t < 2048) ? (website + (size_t)t * NLET)
                                         : (payload + (size_t)(t - 2048) * NLET);
            x0 = xp[2 * lane];
            x1 = xp[2 * lane + 1];
        }
#pragma unroll
        for (int l = 0; l < NLAYERS; ++l) {
            const int s = t * NLAYERS + l + 1;  // step being produced (1..32768)
            const int par = s & 1;

            // ---- compute this wave's unit: 4 gate dot-products over h + x ----
            float2 hv[8];
#pragma unroll
            for (int p = 0; p < 8; ++p)
                hv[p] = *(const float2*)&h_lds[2 * lane + 128 * p];
            const u32x4* rr = (const u32x4*)res_lds + ((u * NLAYERS + l) * 4) * 64 + lane;
            const u32x4 rg0 = rr[0];
            const u32x4 rg1 = rr[64];
            const u32x4 rg2 = rr[128];
            const u32x4 rg3 = rr[192];

            // ---- bf16 hi-part dot products ----
            float acc0 = 0.f, acc1 = 0.f, acc2 = 0.f, acc3 = 0.f;
#pragma unroll
            for (int p = 0; p < 8; ++p) {
                const float hA = hv[p].x, hB = hv[p].y;
                uint32_t w;
                w = wh[l][0][p]; acc0 = fmaf(bflo(w), hA, acc0); acc0 = fmaf(bfhi(w), hB, acc0);
                w = wh[l][1][p]; acc1 = fmaf(bflo(w), hA, acc1); acc1 = fmaf(bfhi(w), hB, acc1);
                w = wh[l][2][p]; acc2 = fmaf(bflo(w), hA, acc2); acc2 = fmaf(bfhi(w), hB, acc2);
                w = wh[l][3][p]; acc3 = fmaf(bflo(w), hA, acc3); acc3 = fmaf(bfhi(w), hB, acc3);
            }
            // ---- int8 residual correction (scale 2^-20) ----
            float ra0 = 0.f, ra1 = 0.f, ra2 = 0.f, ra3 = 0.f;
#pragma unroll
            for (int p = 0; p < 8; ++p) {
                const float hA = hv[p].x, hB = hv[p].y;
                const int b0 = 2 * (p & 1), b1 = 2 * (p & 1) + 1;
                uint32_t w;
                w = rg0[p >> 1]; ra0 = fmaf(SBYTE(w, b0), hA, ra0); ra0 = fmaf(SBYTE(w, b1), hB, ra0);
                w = rg1[p >> 1]; ra1 = fmaf(SBYTE(w, b0), hA, ra1); ra1 = fmaf(SBYTE(w, b1), hB, ra1);
                w = rg2[p >> 1]; ra2 = fmaf(SBYTE(w, b0), hA, ra2); ra2 = fmaf(SBYTE(w, b1), hB, ra2);
                w = rg3[p >> 1]; ra3 = fmaf(SBYTE(w, b0), hA, ra3); ra3 = fmaf(SBYTE(w, b1), hB, ra3);
            }
            acc0 = fmaf(ra0, 0x1.0p-20f, acc0);
            acc1 = fmaf(ra1, 0x1.0p-20f, acc1);
            acc2 = fmaf(ra2, 0x1.0p-20f, acc2);
            acc3 = fmaf(ra3, 0x1.0p-20f, acc3);
            // ---- exact fp32 x contribution ----
            acc0 = fmaf(wxf[l][0][0], x0, acc0); acc0 = fmaf(wxf[l][0][1], x1, acc0);
            acc1 = fmaf(wxf[l][1][0], x0, acc1); acc1 = fmaf(wxf[l][1][1], x1, acc1);
            acc2 = fmaf(wxf[l][2][0], x0, acc2); acc2 = fmaf(wxf[l][2][1], x1, acc2);
            acc3 = fmaf(wxf[l][3][0], x0, acc3); acc3 = fmaf(wxf[l][3][1], x1, acc3);

#pragma unroll
            for (int mm = 32; mm > 0; mm >>= 1) {
                acc0 += __shfl_xor(acc0, mm, 64);
                acc1 += __shfl_xor(acc1, mm, 64);
                acc2 += __shfl_xor(acc2, mm, 64);
                acc3 += __shfl_xor(acc3, mm, 64);
            }
            const float gi = sigm(acc0 + bias[l][0]);
            const float gf = sigm(acc1 + bias[l][1]);
            const float gg = tanh_f(acc2 + bias[l][2]);
            const float go = sigm(acc3 + bias[l][3]);
            c = fmaf(gf, c, gi * gg);
            const float hn = go * tanh_f(c);
            if (lane == 0) h_new[u] = hn;
            __syncthreads();  // h_new ready; everyone done reading h_lds

            // ---- push FIRST: pack 4x24-bit h + tag into ONE 16-B chunk per copy ----
            if (tid < ncopies) {
                const uint32_t t0 = rnd24(h_new[0]);
                const uint32_t t1 = rnd24(h_new[1]);
                const uint32_t t2 = rnd24(h_new[2]);
                const uint32_t t3 = rnd24(h_new[3]);
                u32x4 d;
                d.x = (t0 << 8) | (t1 >> 16);
                d.y = (t1 << 16) | (t2 >> 8);
                d.z = (t2 << 24) | t3;
                d.w = (uint32_t)s;
                char* dst = mail + ((size_t)((tid * 2 + par) * 256 + b)) * 16;
                store_coh_x4(dst, d);
            }

            // ---- paced poll: sleep until data is probably ready, THEN load ----
            {
                const char* srcp = mail + ((size_t)((rcopy * 2 + par) * 256 + tid)) * 16;
                for (int i = 0; i < dl; ++i) __builtin_amdgcn_s_sleep(8);
                u32x4 a;
                int retries = 0;
                for (;;) {
                    load_coh_x4(srcp, a);
                    if (a.w == (uint32_t)s) break;
                    ++retries;
                    __builtin_amdgcn_s_sleep(8);
                }
                // adapt: first-poll hit -> poll a bit earlier next step;
                // misses -> push the first poll later by the observed shortfall.
                dl = (retries == 0) ? (dl > 0 ? dl - 1 : 0)
                                    : ((dl + retries > 48) ? 48 : dl + retries);
                h_lds[4 * tid + 0] = __uint_as_float(a.x & 0xFFFFFF00u);
                h_lds[4 * tid + 1] = __uint_as_float(((a.x & 0xFFu) << 24) | ((a.y >> 16) << 8));
                h_lds[4 * tid + 2] = __uint_as_float(((a.y & 0xFFFFu) << 16) | ((a.z >> 24) << 8));
                h_lds[4 * tid + 3] = __uint_as_float((a.z & 0xFFFFFFu) << 8);
            }
            __syncthreads();  // h_lds now holds h(s)
        }
    }

    if (lane == 0) c_out[k] = c;
}

// ---------- kernel 2: head — out = sigmoid(W_out @ (W_lin@c + b_lin) + b_out) ----------
__global__ void head_kernel(const float* __restrict__ c_out, const float* __restrict__ W_lin,
                            const float* __restrict__ b_lin, const float* __restrict__ W_out,
                            const float* __restrict__ b_out, float* out) {
    const int lane = threadIdx.x;  // 64 threads, one wave
    float cv[16];
    const float4* cp = (const float4*)(c_out + lane * 16);
#pragma unroll
    for (int q = 0; q < 4; ++q) {
        float4 v = cp[q];
        cv[4 * q + 0] = v.x;
        cv[4 * q + 1] = v.y;
        cv[4 * q + 2] = v.z;
        cv[4 * q + 3] = v.w;
    }
    float fsum = 0.f;
#pragma unroll
    for (int i = 0; i < 16; ++i) {
        const float* w = W_lin + (size_t)i * HID + lane * 16;
        float a = 0.f;
#pragma unroll
        for (int m = 0; m < 16; ++m) a = fmaf(w[m], cv[m], a);
#pragma unroll
        for (int mm = 32; mm > 0; mm >>= 1) a += __shfl_xor(a, mm, 64);
        fsum = fmaf(W_out[i], a + b_lin[i], fsum);
    }
    if (lane == 0) out[0] = sigm(fsum + b_out[0]);
}

extern "C" void kernel_launch(void* const* d_in, const int* in_sizes, int n_in, void* d_out,
                              int out_size, void* d_ws, size_t ws_size, hipStream_t stream) {
    (void)in_sizes; (void)n_in; (void)out_size;
    const float* website = (const float*)d_in[0];
    const float* payload = (const float*)d_in[1];
    const float* W_ih = (const float*)d_in[2];
    const float* W_hh = (const float*)d_in[3];
    const float* b_ih = (const float*)d_in[4];
    const float* b_hh = (const float*)d_in[5];
    const float* W_lin = (const float*)d_in[6];
    const float* b_lin = (const float*)d_in[7];
    const float* W_out = (const float*)d_in[8];
    const float* b_out = (const float*)d_in[9];

    // mailbox replicas: ncopies * 2(par) * 256(producers) * 16B = ncopies * 8 KiB
    int ncopies = 64;
    while (ncopies > 1 && (size_t)ncopies * 8192 + 4096 > ws_size) ncopies >>= 1;
    char* mail = (char*)d_ws;
    float* c_out = (float*)((char*)d_ws + (size_t)ncopies * 8192);

    hipMemsetAsync(mail, 0, (size_t)ncopies * 8192, stream);  // zero tags (s starts at 1)
    // 128 KiB dynamic LDS for int8 weight residuals (gfx950: 160 KiB/CU available)
    lstm_persistent<<<256, 256, 131072, stream>>>(website, payload, W_ih, W_hh, b_ih, b_hh,
                                                  mail, c_out, ncopies);
    head_kernel<<<1, 64, 0, stream>>>(c_out, W_lin, b_lin, W_out, b_out, (float*)d_out);
}

// Round 6
// 278712.036 us; speedup vs baseline: 1.3280x; 1.0172x over previous
//
#include <hip/hip_runtime.h>
#include <stdint.h>

#define HID 1024
#define NLAYERS 8
#define NLET 100
#define T_TOTAL 4096

typedef uint32_t u32x4 __attribute__((ext_vector_type(4)));

// ---------- helpers ----------
__device__ __forceinline__ uint32_t f2bf(float f) {
    uint32_t u = __float_as_uint(f);
    return (u + 0x7FFFu + ((u >> 16) & 1u)) >> 16;
}
__device__ __forceinline__ float bflo(uint32_t p) { return __uint_as_float(p << 16); }
__device__ __forceinline__ float bfhi(uint32_t p) { return __uint_as_float(p & 0xFFFF0000u); }
__device__ __forceinline__ float sigm(float x) { return 1.0f / (1.0f + __expf(-x)); }
__device__ __forceinline__ float tanh_f(float x) {
    float xx = fminf(fmaxf(x, -15.0f), 15.0f);
    float e = __expf(2.0f * xx);
    return (e - 1.0f) / (e + 1.0f);
}
// signed byte b (0..3) of word w, as float
#define SBYTE(w, b) ((float)((int)((w) << (24 - 8 * (b))) >> 24))
// round fp32 bit pattern to 24-bit (drop low 8 mantissa bits, round-half-up).
// |h|<1 (tanh-bounded) so the +0x80 carry stays inside the same sign monotone range.
__device__ __forceinline__ uint32_t rnd24(float f) {
    return (__float_as_uint(f) + 0x80u) >> 8;
}

// device-coherent (bypass L1+L2) wide ops
__device__ __forceinline__ void store_coh_x4(void* p, u32x4 d) {
    asm volatile("global_store_dwordx4 %0, %1, off sc0 sc1" ::"v"(p), "v"(d) : "memory");
}
// 64-B coherent load: 4 x dwordx4 from one base address (offsets 0/16/32/48)
__device__ __forceinline__ void load_coh_64(const void* p, u32x4& a, u32x4& b, u32x4& c,
                                            u32x4& d) {
    asm volatile(
        "global_load_dwordx4 %0, %4, off sc0 sc1\n\t"
        "global_load_dwordx4 %1, %4, off offset:16 sc0 sc1\n\t"
        "global_load_dwordx4 %2, %4, off offset:32 sc0 sc1\n\t"
        "global_load_dwordx4 %3, %4, off offset:48 sc0 sc1\n\t"
        "s_waitcnt vmcnt(0)"
        : "=v"(a), "=v"(b), "=v"(c), "=v"(d)
        : "v"(p)
        : "memory");
}

// ---------- kernel 1: persistent stacked-LSTM scan ----------
// 256 blocks x 256 threads (4 waves), 1 block/CU. Block b owns units {4b..4b+3};
// wave u owns unit k=4b+u for ALL 8 layers.
// Precision: h-weights = packed bf16 pairs in regs + int8 residual (scale 2^-20) in
// LDS (128 KiB) -> effective weight error <= 2^-21. x-weights exact fp32 in regs.
// Mailbox: 16-B self-contained chunk per producer (4 x 24-bit h + 32-bit step tag).
// mail layout: [(copy*2 + parity)*256 + producer] * 16 bytes.
//
// R1/R4/R5 evidence: profiled duration is LINEAR in coherent-read traffic
// (~3.0 us per MB across all three rounds). The dominant waste: during the poll,
// all 4 waves executed the same tid-indexed loads -> the block read its 4-KB
// mailbox copy FOUR times (sc1 bypasses L2; nothing dedups). SINGLE-WAVE POLLING:
// only wave 0 polls; each lane owns 4 producers (64 B), checks 4 tags, unpacks
// 16 h-values to h_lds. Waves 1-3 go straight to the barrier. 4x less poll traffic.
// Protocol safety (unchanged): producer can't publish s+2 (same parity slot as s)
// before its block consumed s+1, which requires ALL blocks pushed s+1, which
// requires they consumed s. So no pending chunk is ever overwritten.
__global__ void __launch_bounds__(256, 1)
lstm_persistent(const float* __restrict__ website, const float* __restrict__ payload,
                const float* __restrict__ W_ih, const float* __restrict__ W_hh,
                const float* __restrict__ b_ih, const float* __restrict__ b_hh,
                char* mail, float* c_out, int ncopies) {
    __shared__ float h_lds[HID];
    __shared__ float h_new[4];
    extern __shared__ __align__(16) uint8_t res_lds[];  // 4*8*4*64*16 = 128 KiB

    const int tid = threadIdx.x;    // 0..255
    const int b = blockIdx.x;       // 0..255
    const int u = tid >> 6;         // wave 0..3 = unit within block
    const int lane = tid & 63;
    const int k = b * 4 + u;        // global hidden unit
    const int rcopy = b & (ncopies - 1);

    // ---- one-time: pack weights (bf16 hi in regs, int8 residual in LDS) ----
    uint32_t wh[NLAYERS][4][8];  // [layer][gate][pair p] -> cols (2L+128p, 2L+128p+1)
    float wxf[NLAYERS][4][2];    // exact fp32 x-weights (cols 2L, 2L+1), zero for lanes >= 50
    float bias[NLAYERS][4];
#pragma unroll
    for (int l = 0; l < NLAYERS; ++l) {
#pragma unroll
        for (int g = 0; g < 4; ++g) {
            const int row = 1024 * g + k;
            const float* src = W_hh + ((size_t)(l * 4096 + row)) * 1024;
            uint32_t rb[4];
#pragma unroll
            for (int p = 0; p < 8; ++p) {
                const int c0 = 2 * lane + 128 * p;
                const float w0 = src[c0], w1 = src[c0 + 1];
                const uint32_t pk = f2bf(w0) | (f2bf(w1) << 16);
                wh[l][g][p] = pk;
                // residual, quantized at scale 2^-20 (max |r| = 6.1e-5 < 127*2^-20)
                const float r0 = (w0 - bflo(pk)) * 1048576.0f;
                const float r1 = (w1 - bfhi(pk)) * 1048576.0f;
                const int i0 = __float2int_rn(fminf(fmaxf(r0, -127.0f), 127.0f));
                const int i1 = __float2int_rn(fminf(fmaxf(r1, -127.0f), 127.0f));
                const uint32_t byt = ((uint32_t)i0 & 0xFFu) | (((uint32_t)i1 & 0xFFu) << 8);
                if ((p & 1) == 0) rb[p >> 1] = byt;
                else rb[p >> 1] |= (byt << 16);
            }
            {
                u32x4 v;
                v.x = rb[0]; v.y = rb[1]; v.z = rb[2]; v.w = rb[3];
                u32x4* dst = (u32x4*)res_lds + (((u * NLAYERS + l) * 4 + g) * 64 + lane);
                *dst = v;
            }
            if (lane < 50) {
                const float* sx = W_ih + ((size_t)(l * 4096 + row)) * NLET + 2 * lane;
                wxf[l][g][0] = sx[0];
                wxf[l][g][1] = sx[1];
            } else {
                wxf[l][g][0] = 0.f;
                wxf[l][g][1] = 0.f;
            }
            bias[l][g] = b_ih[l * 4096 + row] + b_hh[l * 4096 + row];
        }
    }

    // init h(0)=0, c(0)=0
    ((float4*)h_lds)[tid] = make_float4(0.f, 0.f, 0.f, 0.f);
    float c = 0.0f;
    // adaptive poll delay (wave 0 only), units of s_sleep(8) ~= 512 cycles ~= 0.24us.
    int dl = 6;
    __syncthreads();

    for (int t = 0; t < T_TOTAL; ++t) {
        // x for this timestep (shared by all 8 layers)
        float x0 = 0.f, x1 = 0.f;
        if (lane < 50) {
            const float* xp = (t < 2048) ? (website + (size_t)t * NLET)
                                         : (payload + (size_t)(t - 2048) * NLET);
            x0 = xp[2 * lane];
            x1 = xp[2 * lane + 1];
        }
#pragma unroll
        for (int l = 0; l < NLAYERS; ++l) {
            const int s = t * NLAYERS + l + 1;  // step being produced (1..32768)
            const int par = s & 1;

            // ---- compute this wave's unit: 4 gate dot-products over h + x ----
            float2 hv[8];
#pragma unroll
            for (int p = 0; p < 8; ++p)
                hv[p] = *(const float2*)&h_lds[2 * lane + 128 * p];
            const u32x4* rr = (const u32x4*)res_lds + ((u * NLAYERS + l) * 4) * 64 + lane;
            const u32x4 rg0 = rr[0];
            const u32x4 rg1 = rr[64];
            const u32x4 rg2 = rr[128];
            const u32x4 rg3 = rr[192];

            // ---- bf16 hi-part dot products ----
            float acc0 = 0.f, acc1 = 0.f, acc2 = 0.f, acc3 = 0.f;
#pragma unroll
            for (int p = 0; p < 8; ++p) {
                const float hA = hv[p].x, hB = hv[p].y;
                uint32_t w;
                w = wh[l][0][p]; acc0 = fmaf(bflo(w), hA, acc0); acc0 = fmaf(bfhi(w), hB, acc0);
                w = wh[l][1][p]; acc1 = fmaf(bflo(w), hA, acc1); acc1 = fmaf(bfhi(w), hB, acc1);
                w = wh[l][2][p]; acc2 = fmaf(bflo(w), hA, acc2); acc2 = fmaf(bfhi(w), hB, acc2);
                w = wh[l][3][p]; acc3 = fmaf(bflo(w), hA, acc3); acc3 = fmaf(bfhi(w), hB, acc3);
            }
            // ---- int8 residual correction (scale 2^-20) ----
            float ra0 = 0.f, ra1 = 0.f, ra2 = 0.f, ra3 = 0.f;
#pragma unroll
            for (int p = 0; p < 8; ++p) {
                const float hA = hv[p].x, hB = hv[p].y;
                const int b0 = 2 * (p & 1), b1 = 2 * (p & 1) + 1;
                uint32_t w;
                w = rg0[p >> 1]; ra0 = fmaf(SBYTE(w, b0), hA, ra0); ra0 = fmaf(SBYTE(w, b1), hB, ra0);
                w = rg1[p >> 1]; ra1 = fmaf(SBYTE(w, b0), hA, ra1); ra1 = fmaf(SBYTE(w, b1), hB, ra1);
                w = rg2[p >> 1]; ra2 = fmaf(SBYTE(w, b0), hA, ra2); ra2 = fmaf(SBYTE(w, b1), hB, ra2);
                w = rg3[p >> 1]; ra3 = fmaf(SBYTE(w, b0), hA, ra3); ra3 = fmaf(SBYTE(w, b1), hB, ra3);
            }
            acc0 = fmaf(ra0, 0x1.0p-20f, acc0);
            acc1 = fmaf(ra1, 0x1.0p-20f, acc1);
            acc2 = fmaf(ra2, 0x1.0p-20f, acc2);
            acc3 = fmaf(ra3, 0x1.0p-20f, acc3);
            // ---- exact fp32 x contribution ----
            acc0 = fmaf(wxf[l][0][0], x0, acc0); acc0 = fmaf(wxf[l][0][1], x1, acc0);
            acc1 = fmaf(wxf[l][1][0], x0, acc1); acc1 = fmaf(wxf[l][1][1], x1, acc1);
            acc2 = fmaf(wxf[l][2][0], x0, acc2); acc2 = fmaf(wxf[l][2][1], x1, acc2);
            acc3 = fmaf(wxf[l][3][0], x0, acc3); acc3 = fmaf(wxf[l][3][1], x1, acc3);

#pragma unroll
            for (int mm = 32; mm > 0; mm >>= 1) {
                acc0 += __shfl_xor(acc0, mm, 64);
                acc1 += __shfl_xor(acc1, mm, 64);
                acc2 += __shfl_xor(acc2, mm, 64);
                acc3 += __shfl_xor(acc3, mm, 64);
            }
            const float gi = sigm(acc0 + bias[l][0]);
            const float gf = sigm(acc1 + bias[l][1]);
            const float gg = tanh_f(acc2 + bias[l][2]);
            const float go = sigm(acc3 + bias[l][3]);
            c = fmaf(gf, c, gi * gg);
            const float hn = go * tanh_f(c);
            if (lane == 0) h_new[u] = hn;
            __syncthreads();  // h_new ready; everyone done reading h_lds

            // ---- wave 0 only: push to every copy, then paced single-wave poll ----
            if (tid < 64) {
                // push: pack 4x24-bit h + tag into ONE 16-B chunk per copy
                if (tid < ncopies) {
                    const uint32_t t0 = rnd24(h_new[0]);
                    const uint32_t t1 = rnd24(h_new[1]);
                    const uint32_t t2 = rnd24(h_new[2]);
                    const uint32_t t3 = rnd24(h_new[3]);
                    u32x4 d;
                    d.x = (t0 << 8) | (t1 >> 16);
                    d.y = (t1 << 16) | (t2 >> 8);
                    d.z = (t2 << 24) | t3;
                    d.w = (uint32_t)s;
                    char* dst = mail + ((size_t)((tid * 2 + par) * 256 + b)) * 16;
                    store_coh_x4(dst, d);
                }

                // poll: lane owns producers 4*lane..4*lane+3 (64 B contiguous)
                const char* srcp =
                    mail + ((size_t)((rcopy * 2 + par) * 256 + 4 * lane)) * 16;
                for (int i = 0; i < dl; ++i) __builtin_amdgcn_s_sleep(8);
                u32x4 a0, a1, a2, a3;
                int retries = 0;
                for (;;) {
                    load_coh_64(srcp, a0, a1, a2, a3);
                    if (a0.w == (uint32_t)s && a1.w == (uint32_t)s &&
                        a2.w == (uint32_t)s && a3.w == (uint32_t)s)
                        break;
                    ++retries;
                    __builtin_amdgcn_s_sleep(8);
                }
                dl = (retries == 0) ? (dl > 0 ? dl - 1 : 0)
                                    : ((dl + retries > 48) ? 48 : dl + retries);
                // unpack 4 chunks -> 16 h values -> h_lds[16*lane .. 16*lane+15]
                float4* hw = (float4*)&h_lds[16 * lane];
                hw[0] = make_float4(
                    __uint_as_float(a0.x & 0xFFFFFF00u),
                    __uint_as_float(((a0.x & 0xFFu) << 24) | ((a0.y >> 16) << 8)),
                    __uint_as_float(((a0.y & 0xFFFFu) << 16) | ((a0.z >> 24) << 8)),
                    __uint_as_float((a0.z & 0xFFFFFFu) << 8));
                hw[1] = make_float4(
                    __uint_as_float(a1.x & 0xFFFFFF00u),
                    __uint_as_float(((a1.x & 0xFFu) << 24) | ((a1.y >> 16) << 8)),
                    __uint_as_float(((a1.y & 0xFFFFu) << 16) | ((a1.z >> 24) << 8)),
                    __uint_as_float((a1.z & 0xFFFFFFu) << 8));
                hw[2] = make_float4(
                    __uint_as_float(a2.x & 0xFFFFFF00u),
                    __uint_as_float(((a2.x & 0xFFu) << 24) | ((a2.y >> 16) << 8)),
                    __uint_as_float(((a2.y & 0xFFFFu) << 16) | ((a2.z >> 24) << 8)),
                    __uint_as_float((a2.z & 0xFFFFFFu) << 8));
                hw[3] = make_float4(
                    __uint_as_float(a3.x & 0xFFFFFF00u),
                    __uint_as_float(((a3.x & 0xFFu) << 24) | ((a3.y >> 16) << 8)),
                    __uint_as_float(((a3.y & 0xFFFFu) << 16) | ((a3.z >> 24) << 8)),
                    __uint_as_float((a3.z & 0xFFFFFFu) << 8));
            }
            __syncthreads();  // h_lds now holds h(s)
        }
    }

    if (lane == 0) c_out[k] = c;
}

// ---------- kernel 2: head — out = sigmoid(W_out @ (W_lin@c + b_lin) + b_out) ----------
__global__ void head_kernel(const float* __restrict__ c_out, const float* __restrict__ W_lin,
                            const float* __restrict__ b_lin, const float* __restrict__ W_out,
                            const float* __restrict__ b_out, float* out) {
    const int lane = threadIdx.x;  // 64 threads, one wave
    float cv[16];
    const float4* cp = (const float4*)(c_out + lane * 16);
#pragma unroll
    for (int q = 0; q < 4; ++q) {
        float4 v = cp[q];
        cv[4 * q + 0] = v.x;
        cv[4 * q + 1] = v.y;
        cv[4 * q + 2] = v.z;
        cv[4 * q + 3] = v.w;
    }
    float fsum = 0.f;
#pragma unroll
    for (int i = 0; i < 16; ++i) {
        const float* w = W_lin + (size_t)i * HID + lane * 16;
        float a = 0.f;
#pragma unroll
        for (int m = 0; m < 16; ++m) a = fmaf(w[m], cv[m], a);
#pragma unroll
        for (int mm = 32; mm > 0; mm >>= 1) a += __shfl_xor(a, mm, 64);
        fsum = fmaf(W_out[i], a + b_lin[i], fsum);
    }
    if (lane == 0) out[0] = sigm(fsum + b_out[0]);
}

extern "C" void kernel_launch(void* const* d_in, const int* in_sizes, int n_in, void* d_out,
                              int out_size, void* d_ws, size_t ws_size, hipStream_t stream) {
    (void)in_sizes; (void)n_in; (void)out_size;
    const float* website = (const float*)d_in[0];
    const float* payload = (const float*)d_in[1];
    const float* W_ih = (const float*)d_in[2];
    const float* W_hh = (const float*)d_in[3];
    const float* b_ih = (const float*)d_in[4];
    const float* b_hh = (const float*)d_in[5];
    const float* W_lin = (const float*)d_in[6];
    const float* b_lin = (const float*)d_in[7];
    const float* W_out = (const float*)d_in[8];
    const float* b_out = (const float*)d_in[9];

    // mailbox replicas: ncopies * 2(par) * 256(producers) * 16B = ncopies * 8 KiB
    int ncopies = 64;
    while (ncopies > 1 && (size_t)ncopies * 8192 + 4096 > ws_size) ncopies >>= 1;
    char* mail = (char*)d_ws;
    float* c_out = (float*)((char*)d_ws + (size_t)ncopies * 8192);

    hipMemsetAsync(mail, 0, (size_t)ncopies * 8192, stream);  // zero tags (s starts at 1)
    // 128 KiB dynamic LDS for int8 weight residuals (gfx950: 160 KiB/CU available)
    lstm_persistent<<<256, 256, 131072, stream>>>(website, payload, W_ih, W_hh, b_ih, b_hh,
                                                  mail, c_out, ncopies);
    head_kernel<<<1, 64, 0, stream>>>(c_out, W_lin, b_lin, W_out, b_out, (float*)d_out);
}